// Round 1
// baseline (603.147 us; speedup 1.0000x reference)
//
#include <hip/hip_runtime.h>
#include <cstdint>
#include <cstddef>

// Problem constants
#define T_TOKENS 8192
#define DIM      1024
#define HID      2048
#define NE       8
#define HCAP     17408   // 16384 used rows + 8*128 max padding

typedef __attribute__((ext_vector_type(8))) short short8;
typedef __attribute__((ext_vector_type(4))) float f32x4;

__device__ __forceinline__ unsigned short f2bf(float f) {
  unsigned int u = __builtin_bit_cast(unsigned int, f);
  u += 0x7fffu + ((u >> 16) & 1u);   // RNE
  return (unsigned short)(u >> 16);
}

__device__ __forceinline__ void gload16(const void* g, void* lds) {
  __builtin_amdgcn_global_load_lds((const __attribute__((address_space(1))) void*)g,
                                   (__attribute__((address_space(3))) void*)lds,
                                   16, 0, 0);
}

// ---------------- x f32 -> bf16 ----------------
__global__ void cvtx_kernel(const float* __restrict__ in, unsigned short* __restrict__ out) {
  size_t i = ((size_t)blockIdx.x * 256 + threadIdx.x) * 8;
  float4 v0 = *(const float4*)(in + i);
  float4 v1 = *(const float4*)(in + i + 4);
  short8 o;
  o[0] = (short)f2bf(v0.x); o[1] = (short)f2bf(v0.y);
  o[2] = (short)f2bf(v0.z); o[3] = (short)f2bf(v0.w);
  o[4] = (short)f2bf(v1.x); o[5] = (short)f2bf(v1.y);
  o[6] = (short)f2bf(v1.z); o[7] = (short)f2bf(v1.w);
  *(short8*)(out + i) = o;
}

// ------- weights [E][K][N] f32 -> [E][N][K] bf16 (transpose + convert) -------
__global__ void transcvt_kernel(const float* __restrict__ in, unsigned short* __restrict__ out,
                                int K, int N) {
  __shared__ float tile[64][65];
  int e = blockIdx.z;
  int r  = threadIdx.x >> 2;          // 0..63
  int c0 = (threadIdx.x & 3) * 16;    // 0,16,32,48
  const float* src = in + ((size_t)e * K + blockIdx.y * 64 + r) * N + blockIdx.x * 64 + c0;
#pragma unroll
  for (int j = 0; j < 4; j++) {
    float4 v = *(const float4*)(src + j * 4);
    tile[r][c0 + j * 4 + 0] = v.x; tile[r][c0 + j * 4 + 1] = v.y;
    tile[r][c0 + j * 4 + 2] = v.z; tile[r][c0 + j * 4 + 3] = v.w;
  }
  __syncthreads();
  // out row n = bx*64 + r, cols k = by*64 + c0 .. +16
  short8 o0, o1;
#pragma unroll
  for (int j = 0; j < 8; j++) o0[j] = (short)f2bf(tile[c0 + j][r]);
#pragma unroll
  for (int j = 0; j < 8; j++) o1[j] = (short)f2bf(tile[c0 + 8 + j][r]);
  unsigned short* dst = out + ((size_t)e * N + blockIdx.x * 64 + r) * K + blockIdx.y * 64 + c0;
  *(short8*)dst = o0;
  *(short8*)(dst + 8) = o1;
}

// ---------------- gating: logits (f64 accum), top-2, softmax, bucket scatter ----------------
__global__ void gate_kernel(const float* __restrict__ x, const float* __restrict__ gw,
                            int* __restrict__ cnt, int* __restrict__ btok,
                            float* __restrict__ bw) {
  int wid = threadIdx.x >> 6, lane = threadIdx.x & 63;
  int t = blockIdx.x * 4 + wid;
  const float* xr = x + (size_t)t * DIM;
  double acc[NE];
#pragma unroll
  for (int e = 0; e < NE; e++) acc[e] = 0.0;
  for (int i = lane; i < DIM; i += 64) {
    float xv = xr[i];
#pragma unroll
    for (int e = 0; e < NE; e++) acc[e] += (double)xv * (double)gw[e * DIM + i];
  }
#pragma unroll
  for (int e = 0; e < NE; e++) {
    double v = acc[e];
#pragma unroll
    for (int off = 32; off > 0; off >>= 1) v += __shfl_xor(v, off);
    acc[e] = v;
  }
  if (lane == 0) {
    float l[NE];
#pragma unroll
    for (int e = 0; e < NE; e++) l[e] = (float)acc[e];
    int i0 = 0; float v0 = l[0];
#pragma unroll
    for (int e = 1; e < NE; e++) if (l[e] > v0) { v0 = l[e]; i0 = e; }
    int i1 = -1; float v1 = -3.4e38f;
#pragma unroll
    for (int e = 0; e < NE; e++) if (e != i0 && l[e] > v1) { v1 = l[e]; i1 = e; }
    float ew = __expf(v1 - v0);          // v1 <= v0, stable
    float w0 = 1.0f / (1.0f + ew);
    float w1 = ew / (1.0f + ew);
    int p0 = atomicAdd(&cnt[i0], 1);
    btok[i0 * T_TOKENS + p0] = t; bw[i0 * T_TOKENS + p0] = w0;
    int p1 = atomicAdd(&cnt[i1], 1);
    btok[i1 * T_TOKENS + p1] = t; bw[i1 * T_TOKENS + p1] = w1;
  }
}

// ---------------- GEMM1: h = silu(Xe@W1) * (Xe@W3), gathered rows, fused ----------------
// block tile 128(M) x 64(N), BK=64, 4 waves in 2x2, dual B (w1,w3)
__global__ __launch_bounds__(256, 2) void gemm1_kernel(
    const unsigned short* __restrict__ xb, const unsigned short* __restrict__ w1t,
    const unsigned short* __restrict__ w3t, const int* __restrict__ cnt,
    const int* __restrict__ btok, const unsigned short* __restrict__ zbuf,
    unsigned short* __restrict__ h) {
  int e = blockIdx.z;
  int cn = cnt[e];
  int pc = (cn + 127) & ~127;
  int mt = blockIdx.y;
  if (mt * 128 >= pc) return;
  int hoff = 0;
#pragma unroll
  for (int i = 0; i < NE; i++) { int pi = (cnt[i] + 127) & ~127; if (i < e) hoff += pi; }
  int nt = blockIdx.x;

  __shared__ short8 At8[1024];  // [128][64] bf16
  __shared__ short8 B18[512];   // [64][64]
  __shared__ short8 B38[512];   // [64][64]

  int tid = threadIdx.x, wid = tid >> 6, lane = tid & 63;
  int m0 = mt * 128;

  const unsigned short* asrc[4];
#pragma unroll
  for (int rd = 0; rd < 4; rd++) {
    int row = (rd * 4 + wid) * 8 + (lane >> 3);
    int r = m0 + row;
    asrc[rd] = (r < cn) ? (xb + (size_t)btok[e * T_TOKENS + r] * DIM + (lane & 7) * 8)
                        : (zbuf + (lane & 7) * 8);
  }
  const unsigned short* b1s[2]; const unsigned short* b3s[2];
#pragma unroll
  for (int rd = 0; rd < 2; rd++) {
    int row = (rd * 4 + wid) * 8 + (lane >> 3);
    size_t o = ((size_t)e * HID + nt * 64 + row) * DIM + (lane & 7) * 8;
    b1s[rd] = w1t + o; b3s[rd] = w3t + o;
  }

  f32x4 zero = {0.f, 0.f, 0.f, 0.f};
  f32x4 acc1[4][2], acc3[4][2];
#pragma unroll
  for (int m = 0; m < 4; m++)
#pragma unroll
    for (int n = 0; n < 2; n++) { acc1[m][n] = zero; acc3[m][n] = zero; }

  int wr = wid >> 1, wc = wid & 1;
  const unsigned short* At = (const unsigned short*)At8;
  const unsigned short* B1 = (const unsigned short*)B18;
  const unsigned short* B3 = (const unsigned short*)B38;

  for (int kt = 0; kt < DIM / 64; kt++) {
    int ko = kt * 64;
#pragma unroll
    for (int rd = 0; rd < 4; rd++)
      gload16(asrc[rd] + ko, (char*)At8 + (rd * 4 + wid) * 1024);
#pragma unroll
    for (int rd = 0; rd < 2; rd++) {
      gload16(b1s[rd] + ko, (char*)B18 + (rd * 4 + wid) * 1024);
      gload16(b3s[rd] + ko, (char*)B38 + (rd * 4 + wid) * 1024);
    }
    __syncthreads();
#pragma unroll
    for (int ks = 0; ks < 2; ks++) {
      short8 a[4], f1[2], f3[2];
#pragma unroll
      for (int m = 0; m < 4; m++)
        a[m] = *(const short8*)(At + (wr * 64 + m * 16 + (lane & 15)) * 64 + ks * 32 + (lane >> 4) * 8);
#pragma unroll
      for (int n = 0; n < 2; n++) {
        int rb = (wc * 32 + n * 16 + (lane & 15)) * 64 + ks * 32 + (lane >> 4) * 8;
        f1[n] = *(const short8*)(B1 + rb);
        f3[n] = *(const short8*)(B3 + rb);
      }
#pragma unroll
      for (int m = 0; m < 4; m++)
#pragma unroll
        for (int n = 0; n < 2; n++) {
          acc1[m][n] = __builtin_amdgcn_mfma_f32_16x16x32_bf16(a[m], f1[n], acc1[m][n], 0, 0, 0);
          acc3[m][n] = __builtin_amdgcn_mfma_f32_16x16x32_bf16(a[m], f3[n], acc3[m][n], 0, 0, 0);
        }
    }
    __syncthreads();
  }

#pragma unroll
  for (int m = 0; m < 4; m++)
#pragma unroll
    for (int n = 0; n < 2; n++) {
#pragma unroll
      for (int j = 0; j < 4; j++) {
        float s1 = acc1[m][n][j], s3 = acc3[m][n][j];
        float hv = s1 / (1.0f + __expf(-s1)) * s3;   // silu(s1)*s3
        int row = wr * 64 + m * 16 + (lane >> 4) * 4 + j;
        int col = nt * 64 + wc * 32 + n * 16 + (lane & 15);
        h[(size_t)(hoff + m0 + row) * HID + col] = f2bf(hv);
      }
    }
}

// ---------------- GEMM2: y = h @ W2, scale by gate weight, atomic combine ----------------
// block tile 128(M) x 128(N), BK=64, 4 waves in 2x2
__global__ __launch_bounds__(256, 2) void gemm2_kernel(
    const unsigned short* __restrict__ h, const unsigned short* __restrict__ w2t,
    const int* __restrict__ cnt, const int* __restrict__ btok,
    const float* __restrict__ bw, float* __restrict__ out) {
  int e = blockIdx.z;
  int cn = cnt[e];
  int pc = (cn + 127) & ~127;
  int mt = blockIdx.y;
  if (mt * 128 >= pc) return;
  int hoff = 0;
#pragma unroll
  for (int i = 0; i < NE; i++) { int pi = (cnt[i] + 127) & ~127; if (i < e) hoff += pi; }
  int nt = blockIdx.x;

  __shared__ short8 At8[1024];  // [128][64]
  __shared__ short8 Bt8[1024];  // [128][64]

  int tid = threadIdx.x, wid = tid >> 6, lane = tid & 63;
  int m0 = mt * 128;

  const unsigned short* as[4]; const unsigned short* bs[4];
#pragma unroll
  for (int rd = 0; rd < 4; rd++) {
    int row = (rd * 4 + wid) * 8 + (lane >> 3);
    as[rd] = h + (size_t)(hoff + m0 + row) * HID + (lane & 7) * 8;
    bs[rd] = w2t + ((size_t)e * DIM + nt * 128 + row) * HID + (lane & 7) * 8;
  }

  f32x4 zero = {0.f, 0.f, 0.f, 0.f};
  f32x4 acc[4][4];
#pragma unroll
  for (int m = 0; m < 4; m++)
#pragma unroll
    for (int n = 0; n < 4; n++) acc[m][n] = zero;

  int wr = wid >> 1, wc = wid & 1;
  const unsigned short* At = (const unsigned short*)At8;
  const unsigned short* Bt = (const unsigned short*)Bt8;

  for (int kt = 0; kt < HID / 64; kt++) {
    int ko = kt * 64;
#pragma unroll
    for (int rd = 0; rd < 4; rd++) {
      gload16(as[rd] + ko, (char*)At8 + (rd * 4 + wid) * 1024);
      gload16(bs[rd] + ko, (char*)Bt8 + (rd * 4 + wid) * 1024);
    }
    __syncthreads();
#pragma unroll
    for (int ks = 0; ks < 2; ks++) {
      short8 a[4], b[4];
#pragma unroll
      for (int m = 0; m < 4; m++)
        a[m] = *(const short8*)(At + (wr * 64 + m * 16 + (lane & 15)) * 64 + ks * 32 + (lane >> 4) * 8);
#pragma unroll
      for (int n = 0; n < 4; n++)
        b[n] = *(const short8*)(Bt + (wc * 64 + n * 16 + (lane & 15)) * 64 + ks * 32 + (lane >> 4) * 8);
#pragma unroll
      for (int m = 0; m < 4; m++)
#pragma unroll
        for (int n = 0; n < 4; n++)
          acc[m][n] = __builtin_amdgcn_mfma_f32_16x16x32_bf16(a[m], b[n], acc[m][n], 0, 0, 0);
    }
    __syncthreads();
  }

#pragma unroll
  for (int m = 0; m < 4; m++)
#pragma unroll
    for (int j = 0; j < 4; j++) {
      int r = m0 + wr * 64 + m * 16 + (lane >> 4) * 4 + j;
      if (r < cn) {
        int t = btok[e * T_TOKENS + r];
        float w = bw[e * T_TOKENS + r];
        size_t ob = (size_t)t * DIM + nt * 128 + wc * 64 + (lane & 15);
#pragma unroll
        for (int n = 0; n < 4; n++)
          atomicAdd(out + ob + n * 16, w * acc[m][n][j]);
      }
    }
}

extern "C" void kernel_launch(void* const* d_in, const int* in_sizes, int n_in,
                              void* d_out, int out_size, void* d_ws, size_t ws_size,
                              hipStream_t stream) {
  const float* x  = (const float*)d_in[0];
  const float* gw = (const float*)d_in[1];
  const float* w1 = (const float*)d_in[2];
  const float* w3 = (const float*)d_in[3];
  const float* w2 = (const float*)d_in[4];
  float* out = (float*)d_out;

  // workspace layout (~181 MiB total)
  char* ws = (char*)d_ws;
  unsigned short* W1T = (unsigned short*)ws;                      // [8][2048][1024] bf16
  unsigned short* W3T = W1T + (size_t)NE * HID * DIM;             // [8][2048][1024]
  unsigned short* W2T = W3T + (size_t)NE * HID * DIM;             // [8][1024][2048]
  unsigned short* XB  = W2T + (size_t)NE * DIM * HID;             // [8192][1024]
  unsigned short* H   = XB + (size_t)T_TOKENS * DIM;              // [17408][2048]
  int*   TOK = (int*)(H + (size_t)HCAP * HID);                    // [8][8192]
  float* BW  = (float*)(TOK + NE * T_TOKENS);                     // [8][8192]
  int*   CNT = (int*)(BW + NE * T_TOKENS);                        // [16]
  unsigned short* ZBUF = (unsigned short*)(CNT + 16);             // [1024] zeros

  hipMemsetAsync(d_out, 0, (size_t)out_size * sizeof(float), stream);
  hipMemsetAsync(CNT, 0, 16 * sizeof(int) + 1024 * sizeof(unsigned short), stream);

  cvtx_kernel<<<(T_TOKENS * DIM) / (256 * 8), 256, 0, stream>>>(x, XB);
  transcvt_kernel<<<dim3(HID / 64, DIM / 64, NE), 256, 0, stream>>>(w1, W1T, DIM, HID);
  transcvt_kernel<<<dim3(HID / 64, DIM / 64, NE), 256, 0, stream>>>(w3, W3T, DIM, HID);
  transcvt_kernel<<<dim3(DIM / 64, HID / 64, NE), 256, 0, stream>>>(w2, W2T, HID, DIM);
  gate_kernel<<<T_TOKENS / 4, 256, 0, stream>>>(x, gw, CNT, TOK, BW);
  gemm1_kernel<<<dim3(HID / 64, 64, NE), 256, 0, stream>>>(XB, W1T, W3T, CNT, TOK, ZBUF, H);
  gemm2_kernel<<<dim3(DIM / 128, 64, NE), 256, 0, stream>>>(H, W2T, CNT, TOK, BW, out);
}

// Round 2
// 377.828 us; speedup vs baseline: 1.5964x; 1.5964x over previous
//
#include <hip/hip_runtime.h>
#include <cstdint>
#include <cstddef>

// Problem constants
#define T_TOKENS 8192
#define DIM      1024
#define HID      2048
#define NE       8
#define HCAP     17408   // 16384 used rows + 8*128 max padding

typedef __attribute__((ext_vector_type(8))) short short8;
typedef __attribute__((ext_vector_type(4))) float f32x4;

__device__ __forceinline__ unsigned short f2bf(float f) {
  unsigned int u = __builtin_bit_cast(unsigned int, f);
  u += 0x7fffu + ((u >> 16) & 1u);   // RNE
  return (unsigned short)(u >> 16);
}

__device__ __forceinline__ void gload16(const void* g, void* lds) {
  __builtin_amdgcn_global_load_lds((const __attribute__((address_space(1))) void*)g,
                                   (__attribute__((address_space(3))) void*)lds,
                                   16, 0, 0);
}

// ---------------- x f32 -> bf16 ----------------
__global__ void cvtx_kernel(const float* __restrict__ in, unsigned short* __restrict__ out) {
  size_t i = ((size_t)blockIdx.x * 256 + threadIdx.x) * 8;
  float4 v0 = *(const float4*)(in + i);
  float4 v1 = *(const float4*)(in + i + 4);
  short8 o;
  o[0] = (short)f2bf(v0.x); o[1] = (short)f2bf(v0.y);
  o[2] = (short)f2bf(v0.z); o[3] = (short)f2bf(v0.w);
  o[4] = (short)f2bf(v1.x); o[5] = (short)f2bf(v1.y);
  o[6] = (short)f2bf(v1.z); o[7] = (short)f2bf(v1.w);
  *(short8*)(out + i) = o;
}

// ------- weights [E][K][N] f32 -> [E][N][K] bf16 (transpose + convert) -------
__global__ void transcvt_kernel(const float* __restrict__ in, unsigned short* __restrict__ out,
                                int K, int N) {
  __shared__ float tile[64][65];
  int e = blockIdx.z;
  int r  = threadIdx.x >> 2;          // 0..63
  int c0 = (threadIdx.x & 3) * 16;    // 0,16,32,48
  const float* src = in + ((size_t)e * K + blockIdx.y * 64 + r) * N + blockIdx.x * 64 + c0;
#pragma unroll
  for (int j = 0; j < 4; j++) {
    float4 v = *(const float4*)(src + j * 4);
    tile[r][c0 + j * 4 + 0] = v.x; tile[r][c0 + j * 4 + 1] = v.y;
    tile[r][c0 + j * 4 + 2] = v.z; tile[r][c0 + j * 4 + 3] = v.w;
  }
  __syncthreads();
  short8 o0, o1;
#pragma unroll
  for (int j = 0; j < 8; j++) o0[j] = (short)f2bf(tile[c0 + j][r]);
#pragma unroll
  for (int j = 0; j < 8; j++) o1[j] = (short)f2bf(tile[c0 + 8 + j][r]);
  unsigned short* dst = out + ((size_t)e * N + blockIdx.x * 64 + r) * K + blockIdx.y * 64 + c0;
  *(short8*)dst = o0;
  *(short8*)(dst + 8) = o1;
}

// ---------------- gate phase A: logits (f64 accum), top-2, softmax (no atomics) ----------------
__global__ void gate_kernel(const float* __restrict__ x, const float* __restrict__ gw,
                            int2* __restrict__ sel, float2* __restrict__ wts) {
  int wid = threadIdx.x >> 6, lane = threadIdx.x & 63;
  int t = blockIdx.x * 4 + wid;
  const float* xr = x + (size_t)t * DIM;
  double acc[NE];
#pragma unroll
  for (int e = 0; e < NE; e++) acc[e] = 0.0;
  for (int i = lane; i < DIM; i += 64) {
    float xv = xr[i];
#pragma unroll
    for (int e = 0; e < NE; e++) acc[e] += (double)xv * (double)gw[e * DIM + i];
  }
#pragma unroll
  for (int e = 0; e < NE; e++) {
    double v = acc[e];
#pragma unroll
    for (int off = 32; off > 0; off >>= 1) v += __shfl_xor(v, off);
    acc[e] = v;
  }
  if (lane == 0) {
    float l[NE];
#pragma unroll
    for (int e = 0; e < NE; e++) l[e] = (float)acc[e];
    int i0 = 0; float v0 = l[0];
#pragma unroll
    for (int e = 1; e < NE; e++) if (l[e] > v0) { v0 = l[e]; i0 = e; }
    int i1 = -1; float v1 = -3.4e38f;
#pragma unroll
    for (int e = 0; e < NE; e++) if (e != i0 && l[e] > v1) { v1 = l[e]; i1 = e; }
    float ew = __expf(v1 - v0);          // v1 <= v0, stable
    float w0 = 1.0f / (1.0f + ew);
    float w1 = ew / (1.0f + ew);
    sel[t] = make_int2(i0, i1);
    wts[t] = make_float2(w0, w1);
  }
}

// ---------------- gate phase B: block-aggregated bucket scatter ----------------
__global__ void scatter_kernel(const int2* __restrict__ sel, const float2* __restrict__ wts,
                               int* __restrict__ cnt, int* __restrict__ btok,
                               float* __restrict__ bw) {
  __shared__ int hist[NE];
  __shared__ int base[NE];
  int tid = threadIdx.x;
  if (tid < NE) hist[tid] = 0;
  __syncthreads();
  int t = blockIdx.x * 256 + tid;
  int2 s = sel[t]; float2 w = wts[t];
  int p0 = atomicAdd(&hist[s.x], 1);
  int p1 = atomicAdd(&hist[s.y], 1);
  __syncthreads();
  if (tid < NE) base[tid] = atomicAdd(&cnt[tid], hist[tid]);
  __syncthreads();
  int o0 = base[s.x] + p0;
  btok[s.x * T_TOKENS + o0] = t; bw[s.x * T_TOKENS + o0] = w.x;
  int o1 = base[s.y] + p1;
  btok[s.y * T_TOKENS + o1] = t; bw[s.y * T_TOKENS + o1] = w.y;
}

// ---------------- GEMM1: h = silu(Xe@W1) * (Xe@W3), gathered rows, fused ----------------
// block tile 128(M) x 64(N), BK=64, 4 waves in 2x2, dual B (w1,w3)
// T2 LDS swizzle (rule #21): linear LDS dest via global_load_lds, pre-swizzled
// global source column, XOR-swizzled ds_read address.
__global__ __launch_bounds__(256, 2) void gemm1_kernel(
    const unsigned short* __restrict__ xb, const unsigned short* __restrict__ w1t,
    const unsigned short* __restrict__ w3t, const int* __restrict__ cnt,
    const int* __restrict__ btok, const unsigned short* __restrict__ zbuf,
    unsigned short* __restrict__ h) {
  int e = blockIdx.z;
  int cn = cnt[e];
  int pc = (cn + 127) & ~127;
  int mt = blockIdx.y;
  if (mt * 128 >= pc) return;
  int hoff = 0;
#pragma unroll
  for (int i = 0; i < NE; i++) { int pi = (cnt[i] + 127) & ~127; if (i < e) hoff += pi; }
  int nt = blockIdx.x;

  __shared__ short8 At8[1024];  // [128][64] bf16
  __shared__ short8 B18[512];   // [64][64]
  __shared__ short8 B38[512];   // [64][64]

  int tid = threadIdx.x, wid = tid >> 6, lane = tid & 63;
  int m0 = mt * 128;

  // pre-swizzled global source column: store row (l>>3) gets col ((l&7)^(l>>3))*8
  int swzcol = ((lane & 7) ^ (lane >> 3)) * 8;

  const unsigned short* asrc[4];
#pragma unroll
  for (int rd = 0; rd < 4; rd++) {
    int row = (rd * 4 + wid) * 8 + (lane >> 3);
    int r = m0 + row;
    asrc[rd] = (r < cn) ? (xb + (size_t)btok[e * T_TOKENS + r] * DIM + swzcol)
                        : (zbuf + swzcol);
  }
  const unsigned short* b1s[2]; const unsigned short* b3s[2];
#pragma unroll
  for (int rd = 0; rd < 2; rd++) {
    int row = (rd * 4 + wid) * 8 + (lane >> 3);
    size_t o = ((size_t)e * HID + nt * 64 + row) * DIM + swzcol;
    b1s[rd] = w1t + o; b3s[rd] = w3t + o;
  }

  f32x4 zero = {0.f, 0.f, 0.f, 0.f};
  f32x4 acc1[4][2], acc3[4][2];
#pragma unroll
  for (int m = 0; m < 4; m++)
#pragma unroll
    for (int n = 0; n < 2; n++) { acc1[m][n] = zero; acc3[m][n] = zero; }

  int wr = wid >> 1, wc = wid & 1;
  const char* At = (const char*)At8;
  const char* B1 = (const char*)B18;
  const char* B3 = (const char*)B38;
  int lxor = (lane & 7) << 4;   // read-side XOR: row&7 == lane&7 for fragment rows

  for (int kt = 0; kt < DIM / 64; kt++) {
    int ko = kt * 64;
#pragma unroll
    for (int rd = 0; rd < 4; rd++)
      gload16(asrc[rd] + ko, (char*)At8 + (rd * 4 + wid) * 1024);
#pragma unroll
    for (int rd = 0; rd < 2; rd++) {
      gload16(b1s[rd] + ko, (char*)B18 + (rd * 4 + wid) * 1024);
      gload16(b3s[rd] + ko, (char*)B38 + (rd * 4 + wid) * 1024);
    }
    __syncthreads();
#pragma unroll
    for (int ks = 0; ks < 2; ks++) {
      int cb = (ks * 64 + (lane >> 4) * 16) ^ lxor;
      short8 a[4], f1[2], f3[2];
#pragma unroll
      for (int m = 0; m < 4; m++)
        a[m] = *(const short8*)(At + (wr * 64 + m * 16 + (lane & 15)) * 128 + cb);
#pragma unroll
      for (int n = 0; n < 2; n++) {
        int rb = (wc * 32 + n * 16 + (lane & 15)) * 128 + cb;
        f1[n] = *(const short8*)(B1 + rb);
        f3[n] = *(const short8*)(B3 + rb);
      }
#pragma unroll
      for (int m = 0; m < 4; m++)
#pragma unroll
        for (int n = 0; n < 2; n++) {
          acc1[m][n] = __builtin_amdgcn_mfma_f32_16x16x32_bf16(a[m], f1[n], acc1[m][n], 0, 0, 0);
          acc3[m][n] = __builtin_amdgcn_mfma_f32_16x16x32_bf16(a[m], f3[n], acc3[m][n], 0, 0, 0);
        }
    }
    __syncthreads();
  }

#pragma unroll
  for (int m = 0; m < 4; m++)
#pragma unroll
    for (int n = 0; n < 2; n++) {
#pragma unroll
      for (int j = 0; j < 4; j++) {
        float s1 = acc1[m][n][j], s3 = acc3[m][n][j];
        float hv = s1 / (1.0f + __expf(-s1)) * s3;   // silu(s1)*s3
        int row = wr * 64 + m * 16 + (lane >> 4) * 4 + j;
        int col = nt * 64 + wc * 32 + n * 16 + (lane & 15);
        h[(size_t)(hoff + m0 + row) * HID + col] = f2bf(hv);
      }
    }
}

// ---------------- GEMM2: y = h @ W2, scale by gate weight, atomic combine ----------------
// block tile 128(M) x 128(N), BK=64, 4 waves in 2x2, T2 swizzle as in gemm1
__global__ __launch_bounds__(256, 2) void gemm2_kernel(
    const unsigned short* __restrict__ h, const unsigned short* __restrict__ w2t,
    const int* __restrict__ cnt, const int* __restrict__ btok,
    const float* __restrict__ bw, float* __restrict__ out) {
  int e = blockIdx.z;
  int cn = cnt[e];
  int pc = (cn + 127) & ~127;
  int mt = blockIdx.y;
  if (mt * 128 >= pc) return;
  int hoff = 0;
#pragma unroll
  for (int i = 0; i < NE; i++) { int pi = (cnt[i] + 127) & ~127; if (i < e) hoff += pi; }
  int nt = blockIdx.x;

  __shared__ short8 At8[1024];  // [128][64]
  __shared__ short8 Bt8[1024];  // [128][64]

  int tid = threadIdx.x, wid = tid >> 6, lane = tid & 63;
  int m0 = mt * 128;

  int swzcol = ((lane & 7) ^ (lane >> 3)) * 8;

  const unsigned short* as[4]; const unsigned short* bs[4];
#pragma unroll
  for (int rd = 0; rd < 4; rd++) {
    int row = (rd * 4 + wid) * 8 + (lane >> 3);
    as[rd] = h + (size_t)(hoff + m0 + row) * HID + swzcol;
    bs[rd] = w2t + ((size_t)e * DIM + nt * 128 + row) * HID + swzcol;
  }

  f32x4 zero = {0.f, 0.f, 0.f, 0.f};
  f32x4 acc[4][4];
#pragma unroll
  for (int m = 0; m < 4; m++)
#pragma unroll
    for (int n = 0; n < 4; n++) acc[m][n] = zero;

  int wr = wid >> 1, wc = wid & 1;
  const char* At = (const char*)At8;
  const char* Bt = (const char*)Bt8;
  int lxor = (lane & 7) << 4;

  for (int kt = 0; kt < HID / 64; kt++) {
    int ko = kt * 64;
#pragma unroll
    for (int rd = 0; rd < 4; rd++) {
      gload16(as[rd] + ko, (char*)At8 + (rd * 4 + wid) * 1024);
      gload16(bs[rd] + ko, (char*)Bt8 + (rd * 4 + wid) * 1024);
    }
    __syncthreads();
#pragma unroll
    for (int ks = 0; ks < 2; ks++) {
      int cb = (ks * 64 + (lane >> 4) * 16) ^ lxor;
      short8 a[4], b[4];
#pragma unroll
      for (int m = 0; m < 4; m++)
        a[m] = *(const short8*)(At + (wr * 64 + m * 16 + (lane & 15)) * 128 + cb);
#pragma unroll
      for (int n = 0; n < 4; n++)
        b[n] = *(const short8*)(Bt + (wc * 64 + n * 16 + (lane & 15)) * 128 + cb);
#pragma unroll
      for (int m = 0; m < 4; m++)
#pragma unroll
        for (int n = 0; n < 4; n++)
          acc[m][n] = __builtin_amdgcn_mfma_f32_16x16x32_bf16(a[m], b[n], acc[m][n], 0, 0, 0);
    }
    __syncthreads();
  }

#pragma unroll
  for (int m = 0; m < 4; m++)
#pragma unroll
    for (int j = 0; j < 4; j++) {
      int r = m0 + wr * 64 + m * 16 + (lane >> 4) * 4 + j;
      if (r < cn) {
        int t = btok[e * T_TOKENS + r];
        float w = bw[e * T_TOKENS + r];
        size_t ob = (size_t)t * DIM + nt * 128 + wc * 64 + (lane & 15);
#pragma unroll
        for (int n = 0; n < 4; n++)
          atomicAdd(out + ob + n * 16, w * acc[m][n][j]);
      }
    }
}

extern "C" void kernel_launch(void* const* d_in, const int* in_sizes, int n_in,
                              void* d_out, int out_size, void* d_ws, size_t ws_size,
                              hipStream_t stream) {
  const float* x  = (const float*)d_in[0];
  const float* gw = (const float*)d_in[1];
  const float* w1 = (const float*)d_in[2];
  const float* w3 = (const float*)d_in[3];
  const float* w2 = (const float*)d_in[4];
  float* out = (float*)d_out;

  // workspace layout (~190 MiB total)
  char* ws = (char*)d_ws;
  unsigned short* W1T = (unsigned short*)ws;                      // [8][2048][1024] bf16
  unsigned short* W3T = W1T + (size_t)NE * HID * DIM;             // [8][2048][1024]
  unsigned short* W2T = W3T + (size_t)NE * HID * DIM;             // [8][1024][2048]
  unsigned short* XB  = W2T + (size_t)NE * DIM * HID;             // [8192][1024]
  unsigned short* H   = XB + (size_t)T_TOKENS * DIM;              // [17408][2048]
  int*   TOK = (int*)(H + (size_t)HCAP * HID);                    // [8][8192]
  float* BW  = (float*)(TOK + NE * T_TOKENS);                     // [8][8192]
  int*   CNT = (int*)(BW + NE * T_TOKENS);                        // [16]
  unsigned short* ZBUF = (unsigned short*)(CNT + 16);             // [1024] zeros
  int2*   SEL = (int2*)(ZBUF + 1024);                             // [8192]
  float2* WTS = (float2*)(SEL + T_TOKENS);                        // [8192]

  hipMemsetAsync(d_out, 0, (size_t)out_size * sizeof(float), stream);
  hipMemsetAsync(CNT, 0, 16 * sizeof(int) + 1024 * sizeof(unsigned short), stream);

  cvtx_kernel<<<(T_TOKENS * DIM) / (256 * 8), 256, 0, stream>>>(x, XB);
  transcvt_kernel<<<dim3(HID / 64, DIM / 64, NE), 256, 0, stream>>>(w1, W1T, DIM, HID);
  transcvt_kernel<<<dim3(HID / 64, DIM / 64, NE), 256, 0, stream>>>(w3, W3T, DIM, HID);
  transcvt_kernel<<<dim3(DIM / 64, HID / 64, NE), 256, 0, stream>>>(w2, W2T, HID, DIM);
  gate_kernel<<<T_TOKENS / 4, 256, 0, stream>>>(x, gw, SEL, WTS);
  scatter_kernel<<<T_TOKENS / 256, 256, 0, stream>>>(SEL, WTS, CNT, TOK, BW);
  gemm1_kernel<<<dim3(HID / 64, 64, NE), 256, 0, stream>>>(XB, W1T, W3T, CNT, TOK, ZBUF, H);
  gemm2_kernel<<<dim3(DIM / 128, 64, NE), 256, 0, stream>>>(H, W2T, CNT, TOK, BW, out);
}